// Round 8
// baseline (761.719 us; speedup 1.0000x reference)
//
#include <hip/hip_runtime.h>
#include <cstddef>

#define BB 8
#define JJ 3
#define NN 2048
#define CC 32
#define FF 32
#define NINTER 128
#define JCC 96
#define BN_EPS 1e-5f

#define WSZ ((size_t)BB * JJ * NN * (size_t)NN)  // 100663296 floats

// workspace float offsets
#define WS_Y   ((size_t)0)
#define WS_H   ((size_t)BB * JCC * NN)               // 1572864
#define WS_A1  (WS_H + (size_t)BB * NINTER * NN)     // 3670016
#define WS_B1  (WS_A1 + 96)
#define WS_A2  (WS_B1 + 96)
#define WS_B2  (WS_A2 + 128)
#define WS_WT1 (WS_B2 + 128)                          // [96][128]
#define WS_WT2 (WS_WT1 + (size_t)(JCC * NINTER))      // [128][32]

#define K1_TM 128
#define K1_BK 64
#define WPAD 68   // 68 % 4 == 0 (16B-aligned rows), 68 % 32 == 4 (distinct bank quartets)

// clang-native 16B vector: guaranteed compatible with __builtin_nontemporal_*
typedef float f32x4 __attribute__((ext_vector_type(4)));

// ---------------------------------------------------------------------------
// K1: Y[b, j*32+c, n] = sum_m W[b,j,n,m] * x[b,c,m]   +   d_out[0:WSZ] = W
// grid = B*J*(N/128) = 384 blocks, 256 threads
// ---------------------------------------------------------------------------
__global__ __launch_bounds__(256, 2)
void k1_gmul(const float* __restrict__ W, const float* __restrict__ X,
             float* __restrict__ Wout, float* __restrict__ Y) {
    int blk = blockIdx.x;
    int ntile = blk & 15;          // N/K1_TM = 16
    int bj = blk >> 4;             // 0..23
    int b = bj / JJ;
    int j = bj - b * JJ;
    const float* Wbj = W + (size_t)bj * NN * (size_t)NN;
    float* Wo = Wout + (size_t)bj * NN * (size_t)NN;
    const float* xb = X + (size_t)b * CC * NN;
    int n0 = ntile * K1_TM;

    __shared__ float Wl[K1_TM * WPAD];   // 34816 B
    __shared__ float Xl[CC * WPAD];      //  8704 B

    int t = threadIdx.x;
    int rg = t >> 3;           // 0..31 : row group (rows rg + 32*i)
    int cg = t & 7;            // 0..7  : col group (cols cg + 8*q)
    int srow = t >> 4;         // 0..15 : staging row base
    int sk = (t & 15) << 2;    // 0..60 : staging k offset (floats)

    f32x4 wreg[8];
    f32x4 xreg[2];

    // prefetch chunk 0
#pragma unroll
    for (int i = 0; i < 8; ++i)
        wreg[i] = __builtin_nontemporal_load(
            (const f32x4*)(Wbj + (size_t)(n0 + srow + 16 * i) * NN + sk));
#pragma unroll
    for (int i = 0; i < 2; ++i) {
        int f = t + 256 * i;
        int c = f >> 4;
        int ks = (f & 15) << 2;
        xreg[i] = *(const f32x4*)(xb + (size_t)c * NN + ks);
    }

    float acc[4][4];
#pragma unroll
    for (int r = 0; r < 4; ++r)
#pragma unroll
        for (int q = 0; q < 4; ++q) acc[r][q] = 0.f;

    for (int k0 = 0; k0 < NN; k0 += K1_BK) {
        // commit staged chunk k0 to LDS and to the W copy in d_out
#pragma unroll
        for (int i = 0; i < 8; ++i) {
            int row = srow + 16 * i;
            *(f32x4*)(&Wl[row * WPAD + sk]) = wreg[i];
            __builtin_nontemporal_store(
                wreg[i], (f32x4*)(Wo + (size_t)(n0 + row) * NN + k0 + sk));
        }
#pragma unroll
        for (int i = 0; i < 2; ++i) {
            int f = t + 256 * i;
            int c = f >> 4;
            int ks = (f & 15) << 2;
            *(f32x4*)(&Xl[c * WPAD + ks]) = xreg[i];
        }
        __syncthreads();

        // prefetch next chunk into regs (overlaps with compute below)
        if (k0 + K1_BK < NN) {
            int kn = k0 + K1_BK;
#pragma unroll
            for (int i = 0; i < 8; ++i)
                wreg[i] = __builtin_nontemporal_load(
                    (const f32x4*)(Wbj + (size_t)(n0 + srow + 16 * i) * NN + kn + sk));
#pragma unroll
            for (int i = 0; i < 2; ++i) {
                int f = t + 256 * i;
                int c = f >> 4;
                int ks = (f & 15) << 2;
                xreg[i] = *(const f32x4*)(xb + (size_t)c * NN + kn + ks);
            }
        }

        // compute chunk k0 from LDS
#pragma unroll
        for (int kk = 0; kk < K1_BK; kk += 4) {
            f32x4 wv[4], xv[4];
#pragma unroll
            for (int i = 0; i < 4; ++i)
                wv[i] = *(const f32x4*)(&Wl[(rg + 32 * i) * WPAD + kk]);
#pragma unroll
            for (int i = 0; i < 4; ++i)
                xv[i] = *(const f32x4*)(&Xl[(cg + 8 * i) * WPAD + kk]);
#pragma unroll
            for (int r = 0; r < 4; ++r)
#pragma unroll
                for (int q = 0; q < 4; ++q) {
                    acc[r][q] = fmaf(wv[r].x, xv[q].x, acc[r][q]);
                    acc[r][q] = fmaf(wv[r].y, xv[q].y, acc[r][q]);
                    acc[r][q] = fmaf(wv[r].z, xv[q].z, acc[r][q]);
                    acc[r][q] = fmaf(wv[r].w, xv[q].w, acc[r][q]);
                }
        }
        __syncthreads();
    }

    // write Y[b][j*32 + c][n0 + row]
#pragma unroll
    for (int q = 0; q < 4; ++q) {
        int c = cg + 8 * q;
        float* Yp = Y + ((size_t)b * JCC + j * CC + c) * NN + n0;
#pragma unroll
        for (int r = 0; r < 4; ++r) Yp[rg + 32 * r] = acc[r][q];
    }
}

// ---------------------------------------------------------------------------
// K1s: BN1 stats -> a1,b1 (blocks 0..95); block 96 transposes conv weights
// ---------------------------------------------------------------------------
__global__ void k1s_stats(const float* __restrict__ Y, const float* __restrict__ g1,
                          const float* __restrict__ be1, const float* __restrict__ w1,
                          const float* __restrict__ w2, float* __restrict__ a1,
                          float* __restrict__ b1, float* __restrict__ wT1,
                          float* __restrict__ wT2) {
    int t = threadIdx.x;
    if (blockIdx.x == JCC) {
        for (int idx = t; idx < JCC * NINTER; idx += 256) {
            int jc = idx >> 7, o = idx & 127;
            wT1[idx] = w1[o * JCC + jc];
        }
        for (int idx = t; idx < NINTER * FF; idx += 256) {
            int c2 = idx >> 5, f = idx & 31;
            wT2[idx] = w2[f * NINTER + c2];
        }
        return;
    }
    int jc = blockIdx.x;
    float s = 0.f, sq = 0.f;
#pragma unroll
    for (int i = 0; i < 16; ++i) {
        int f = t + 256 * i;                // float4 index, 0..4095
        int b = f >> 9, pos = f & 511;
        f32x4 y = *(const f32x4*)(Y + ((size_t)b * JCC + jc) * NN + pos * 4);
        s += y.x + y.y + y.z + y.w;
        sq += y.x * y.x + y.y * y.y + y.z * y.z + y.w * y.w;
    }
    for (int off = 32; off > 0; off >>= 1) {
        s += __shfl_down(s, off);
        sq += __shfl_down(sq, off);
    }
    __shared__ float ls[4], lq[4];
    int w = t >> 6;
    if ((t & 63) == 0) { ls[w] = s; lq[w] = sq; }
    __syncthreads();
    if (t == 0) {
        s = ls[0] + ls[1] + ls[2] + ls[3];
        sq = lq[0] + lq[1] + lq[2] + lq[3];
        float mean = s * (1.f / 16384.f);
        float var = sq * (1.f / 16384.f) - mean * mean;
        float A = g1[jc] * rsqrtf(var + BN_EPS);
        a1[jc] = A;
        b1[jc] = be1[jc] - mean * A;
    }
}

// ---------------------------------------------------------------------------
// K2: H[b,o,n] = sum_jc wT1[jc][o] * relu(a1*Y + b1) + conv1_b[o]
// grid = B * (N/32) = 512 blocks, 256 threads
// ---------------------------------------------------------------------------
__global__ __launch_bounds__(256, 4)
void k2_conv1(const float* __restrict__ Y, const float* __restrict__ wT1,
              const float* __restrict__ a1, const float* __restrict__ b1,
              const float* __restrict__ c1b, float* __restrict__ H) {
    int blk = blockIdx.x;
    int b = blk >> 6;
    int n0 = (blk & 63) << 5;
    __shared__ float Z[JCC * 32];
    int t = threadIdx.x;
#pragma unroll
    for (int i = 0; i < 3; ++i) {
        int idx = t + 256 * i;              // float4 index, 0..767
        int jc = idx >> 3, ns = idx & 7;
        f32x4 y = *(const f32x4*)(Y + ((size_t)b * JCC + jc) * NN + n0 + ns * 4);
        float A = a1[jc], Bv = b1[jc];
        f32x4 z;
        z.x = fmaxf(fmaf(A, y.x, Bv), 0.f);
        z.y = fmaxf(fmaf(A, y.y, Bv), 0.f);
        z.z = fmaxf(fmaf(A, y.z, Bv), 0.f);
        z.w = fmaxf(fmaf(A, y.w, Bv), 0.f);
        *(f32x4*)(&Z[jc * 32 + ns * 4]) = z;
    }
    __syncthreads();

    int o = t & 127;
    int nh = t >> 7;       // 0 or 1 -> 16 n's each
    float acc[16];
#pragma unroll
    for (int i = 0; i < 16; ++i) acc[i] = 0.f;
    for (int jc = 0; jc < JCC; ++jc) {
        float wv = wT1[jc * NINTER + o];
        const f32x4* zp = (const f32x4*)(&Z[jc * 32 + nh * 16]);
#pragma unroll
        for (int q = 0; q < 4; ++q) {
            f32x4 z4 = zp[q];
            acc[q * 4 + 0] = fmaf(wv, z4.x, acc[q * 4 + 0]);
            acc[q * 4 + 1] = fmaf(wv, z4.y, acc[q * 4 + 1]);
            acc[q * 4 + 2] = fmaf(wv, z4.z, acc[q * 4 + 2]);
            acc[q * 4 + 3] = fmaf(wv, z4.w, acc[q * 4 + 3]);
        }
    }
    float bias = c1b[o];
#pragma unroll
    for (int q = 0; q < 4; ++q) {
        f32x4 o4 = {acc[q * 4 + 0] + bias, acc[q * 4 + 1] + bias,
                    acc[q * 4 + 2] + bias, acc[q * 4 + 3] + bias};
        *(f32x4*)(H + ((size_t)b * NINTER + o) * NN + n0 + nh * 16 + q * 4) = o4;
    }
}

// ---------------------------------------------------------------------------
// K2s: BN2 stats -> a2, b2 (128 blocks)
// ---------------------------------------------------------------------------
__global__ void k2s_stats(const float* __restrict__ H, const float* __restrict__ g2,
                          const float* __restrict__ be2, float* __restrict__ a2,
                          float* __restrict__ b2) {
    int o = blockIdx.x;
    int t = threadIdx.x;
    float s = 0.f, sq = 0.f;
#pragma unroll
    for (int i = 0; i < 16; ++i) {
        int f = t + 256 * i;
        int b = f >> 9, pos = f & 511;
        f32x4 h = *(const f32x4*)(H + ((size_t)b * NINTER + o) * NN + pos * 4);
        s += h.x + h.y + h.z + h.w;
        sq += h.x * h.x + h.y * h.y + h.z * h.z + h.w * h.w;
    }
    for (int off = 32; off > 0; off >>= 1) {
        s += __shfl_down(s, off);
        sq += __shfl_down(sq, off);
    }
    __shared__ float ls[4], lq[4];
    int w = t >> 6;
    if ((t & 63) == 0) { ls[w] = s; lq[w] = sq; }
    __syncthreads();
    if (t == 0) {
        s = ls[0] + ls[1] + ls[2] + ls[3];
        sq = lq[0] + lq[1] + lq[2] + lq[3];
        float mean = s * (1.f / 16384.f);
        float var = sq * (1.f / 16384.f) - mean * mean;
        float A = g2[o] * rsqrtf(var + BN_EPS);
        a2[o] = A;
        b2[o] = be2[o] - mean * A;
    }
}

// ---------------------------------------------------------------------------
// K3: out[b, 0:32, n] = x ; out[b, 32+f, n] = sum_c2 wT2[c2][f]*relu(a2*H+b2) + c2b
// grid = B * (N/32) = 512 blocks, 256 threads
// ---------------------------------------------------------------------------
__global__ __launch_bounds__(256, 4)
void k3_final(const float* __restrict__ H, const float* __restrict__ X,
              const float* __restrict__ wT2, const float* __restrict__ a2,
              const float* __restrict__ b2, const float* __restrict__ c2b,
              float* __restrict__ out) {
    int blk = blockIdx.x;
    int b = blk >> 6;
    int n0 = (blk & 63) << 5;
    __shared__ float Z[NINTER * 32];
    int t = threadIdx.x;
#pragma unroll
    for (int i = 0; i < 4; ++i) {
        int idx = t + 256 * i;              // float4 index, 0..1023
        int c2 = idx >> 3, ns = idx & 7;
        f32x4 h = *(const f32x4*)(H + ((size_t)b * NINTER + c2) * NN + n0 + ns * 4);
        float A = a2[c2], Bv = b2[c2];
        f32x4 z;
        z.x = fmaxf(fmaf(A, h.x, Bv), 0.f);
        z.y = fmaxf(fmaf(A, h.y, Bv), 0.f);
        z.z = fmaxf(fmaf(A, h.z, Bv), 0.f);
        z.w = fmaxf(fmaf(A, h.w, Bv), 0.f);
        *(f32x4*)(&Z[c2 * 32 + ns * 4]) = z;
    }
    // copy x -> out channels 0..31 (independent of Z)
    {
        int c = t >> 3, ns = t & 7;
        f32x4 xv = *(const f32x4*)(X + ((size_t)b * CC + c) * NN + n0 + ns * 4);
        *(f32x4*)(out + ((size_t)b * 64 + c) * NN + n0 + ns * 4) = xv;
    }
    __syncthreads();

    int f = t & 31;
    int ng = t >> 5;   // 0..7 -> 4 n's each
    float a0 = 0.f, A1 = 0.f, A2v = 0.f, A3 = 0.f;
    for (int c2 = 0; c2 < NINTER; ++c2) {
        float wv = wT2[c2 * FF + f];
        f32x4 z4 = *(const f32x4*)(&Z[c2 * 32 + ng * 4]);
        a0 = fmaf(wv, z4.x, a0);
        A1 = fmaf(wv, z4.y, A1);
        A2v = fmaf(wv, z4.z, A2v);
        A3 = fmaf(wv, z4.w, A3);
    }
    float bias = c2b[f];
    f32x4 o4 = {a0 + bias, A1 + bias, A2v + bias, A3 + bias};
    *(f32x4*)(out + ((size_t)b * 64 + 32 + f) * NN + n0 + ng * 4) = o4;
}

// ---------------------------------------------------------------------------
extern "C" void kernel_launch(void* const* d_in, const int* in_sizes, int n_in,
                              void* d_out, int out_size, void* d_ws, size_t ws_size,
                              hipStream_t stream) {
    const float* W   = (const float*)d_in[0];
    const float* X   = (const float*)d_in[1];
    const float* g1  = (const float*)d_in[2];
    const float* be1 = (const float*)d_in[3];
    const float* w1  = (const float*)d_in[4];
    const float* c1b = (const float*)d_in[5];
    const float* g2  = (const float*)d_in[6];
    const float* be2 = (const float*)d_in[7];
    const float* w2  = (const float*)d_in[8];
    const float* c2b = (const float*)d_in[9];

    float* out = (float*)d_out;
    float* ws  = (float*)d_ws;

    float* Y   = ws + WS_Y;
    float* H   = ws + WS_H;
    float* a1  = ws + WS_A1;
    float* b1  = ws + WS_B1;
    float* a2  = ws + WS_A2;
    float* b2  = ws + WS_B2;
    float* wT1 = ws + WS_WT1;
    float* wT2 = ws + WS_WT2;

    k1_gmul<<<BB * JJ * (NN / K1_TM), 256, 0, stream>>>(W, X, out, Y);
    k1s_stats<<<JCC + 1, 256, 0, stream>>>(Y, g1, be1, w1, w2, a1, b1, wT1, wT2);
    k2_conv1<<<BB * (NN / 32), 256, 0, stream>>>(Y, wT1, a1, b1, c1b, H);
    k2s_stats<<<NINTER, 256, 0, stream>>>(H, g2, be2, a2, b2);
    k3_final<<<BB * (NN / 32), 256, 0, stream>>>(H, X, wT2, a2, b2, c2b, out + WSZ);
}